// Round 2
// baseline (88.351 us; speedup 1.0000x reference)
//
#include <hip/hip_runtime.h>
#include <math.h>

#define TOKENS 16384
#define DIM 2048
#define NE 8
#define BLOCK 512
#define WAVES_PER_BLOCK 8
#define GRID 256
#define TR 4
#define NGROUPS (TOKENS / TR)                  // 4096 token-groups
#define TOTAL_WAVES (GRID * WAVES_PER_BLOCK)   // 2048 waves

__launch_bounds__(BLOCK, 2)
__global__ void router_kernel(const float* __restrict__ x,
                              const float* __restrict__ w_g,
                              const float* __restrict__ w_noise,
                              const float* __restrict__ eps,
                              float* __restrict__ out)
{
    // rows 0..7 = w_g, rows 8..15 = w_noise; natural [16][2048] layout
    __shared__ float wlds[16 * DIM];           // 128 KiB

    const int tid = threadIdx.x;

    // ---- stage weights (coalesced float4) ----
    {
        const float4* g4 = (const float4*)w_g;
        const float4* n4 = (const float4*)w_noise;
        float4* l4 = (float4*)wlds;
        #pragma unroll
        for (int i = tid; i < (NE * DIM) / 4; i += BLOCK) {   // 4096 float4 each array
            l4[i] = g4[i];
            l4[i + (NE * DIM) / 4] = n4[i];
        }
    }
    __syncthreads();

    const int lane = tid & 63;
    const int wave = blockIdx.x * WAVES_PER_BLOCK + (tid >> 6);

    const float4* x4  = (const float4*)x;
    const float4* wl4 = (const float4*)wlds;

    for (int grp = wave; grp < NGROUPS; grp += TOTAL_WAVES) {
        const int t0 = grp * TR;

        float acc_g[NE][TR];
        float acc_n[NE][TR];
        #pragma unroll
        for (int e = 0; e < NE; ++e)
            #pragma unroll
            for (int t = 0; t < TR; ++t) { acc_g[e][t] = 0.f; acc_n[e][t] = 0.f; }

        // lane owns floats [k*256 + lane*4, +4) of each row; float4 idx = k*64 + lane
        float4 xv[TR];
        #pragma unroll
        for (int t = 0; t < TR; ++t)
            xv[t] = x4[(t0 + t) * (DIM / 4) + lane];

        for (int k = 0; k < DIM / 256; ++k) {
            float4 xn[TR];
            if (k < DIM / 256 - 1) {
                #pragma unroll
                for (int t = 0; t < TR; ++t)
                    xn[t] = x4[(t0 + t) * (DIM / 4) + (k + 1) * 64 + lane];
            } else {
                #pragma unroll
                for (int t = 0; t < TR; ++t) xn[t] = xv[t];
            }
            #pragma unroll
            for (int e = 0; e < NE; ++e) {
                const float4 wg = wl4[e * (DIM / 4) + k * 64 + lane];
                const float4 wn = wl4[(NE + e) * (DIM / 4) + k * 64 + lane];
                #pragma unroll
                for (int t = 0; t < TR; ++t) {
                    acc_g[e][t] = fmaf(xv[t].x, wg.x, acc_g[e][t]);
                    acc_g[e][t] = fmaf(xv[t].y, wg.y, acc_g[e][t]);
                    acc_g[e][t] = fmaf(xv[t].z, wg.z, acc_g[e][t]);
                    acc_g[e][t] = fmaf(xv[t].w, wg.w, acc_g[e][t]);
                    acc_n[e][t] = fmaf(xv[t].x, wn.x, acc_n[e][t]);
                    acc_n[e][t] = fmaf(xv[t].y, wn.y, acc_n[e][t]);
                    acc_n[e][t] = fmaf(xv[t].z, wn.z, acc_n[e][t]);
                    acc_n[e][t] = fmaf(xv[t].w, wn.w, acc_n[e][t]);
                }
            }
            #pragma unroll
            for (int t = 0; t < TR; ++t) xv[t] = xn[t];
        }

        // ---- full-wave butterfly reduction: every lane gets the full sums ----
        #pragma unroll
        for (int e = 0; e < NE; ++e) {
            #pragma unroll
            for (int t = 0; t < TR; ++t) {
                float g = acc_g[e][t];
                float n = acc_n[e][t];
                #pragma unroll
                for (int m = 1; m < 64; m <<= 1) {
                    g += __shfl_xor(g, m, 64);
                    n += __shfl_xor(n, m, 64);
                }
                acc_g[e][t] = g;
                acc_n[e][t] = n;
            }
        }

        // ---- epilogue: lane t handles token t0+t (compile-time acc indices) ----
        #pragma unroll
        for (int t = 0; t < TR; ++t) {
            if (lane == t) {
                const int tok = t0 + t;
                float v1 = -INFINITY, v2 = -INFINITY;
                int i1 = 0, i2 = 0;
                #pragma unroll
                for (int e = 0; e < NE; ++e) {
                    const float n = acc_n[e][t];
                    // stable softplus: max(n,0) + log1p(exp(-|n|))
                    const float sp = fmaxf(n, 0.f) + log1pf(expf(-fabsf(n)));
                    const float logit = fmaf(sp, eps[tok * NE + e], acc_g[e][t]);
                    if (logit > v1)      { v2 = v1; i2 = i1; v1 = logit; i1 = e; }
                    else if (logit > v2) { v2 = logit; i2 = e; }
                }
                out[2 * tok]     = v1;
                out[2 * tok + 1] = v2;
                out[2 * TOKENS + 2 * tok]     = (float)i1;
                out[2 * TOKENS + 2 * tok + 1] = (float)i2;
            }
        }
    }
}

extern "C" void kernel_launch(void* const* d_in, const int* in_sizes, int n_in,
                              void* d_out, int out_size, void* d_ws, size_t ws_size,
                              hipStream_t stream) {
    const float* x       = (const float*)d_in[0];
    const float* w_g     = (const float*)d_in[1];
    const float* w_noise = (const float*)d_in[2];
    const float* eps     = (const float*)d_in[3];
    float* out = (float*)d_out;

    router_kernel<<<GRID, BLOCK, 0, stream>>>(x, w_g, w_noise, eps, out);
}

// Round 3
// 33.762 us; speedup vs baseline: 2.6169x; 2.6169x over previous
//
#include <hip/hip_runtime.h>
#include <math.h>

#define TOKENS 16384
#define DIM 2048
#define NE 8
#define NROWS 16                 // rows 0..7 = w_g, 8..15 = w_noise
#define BLOCK 1024
#define WAVES_PER_BLOCK 16
#define GRID 256
#define TR 4
#define NGROUPS (TOKENS / TR)    // 4096 == GRID * WAVES_PER_BLOCK (1 group per wave)

__launch_bounds__(BLOCK, 4)
__global__ void router_kernel(const float* __restrict__ x,
                              const float* __restrict__ w_g,
                              const float* __restrict__ w_noise,
                              const float* __restrict__ eps,
                              float* __restrict__ out)
{
    __shared__ float wlds[NROWS * DIM];      // 128 KiB -> 1 block/CU, 16 waves/CU

    const int tid = threadIdx.x;

    // ---- stage weights (coalesced float4), natural [16][2048] layout ----
    {
        const float4* g4 = (const float4*)w_g;
        const float4* n4 = (const float4*)w_noise;
        float4* l4 = (float4*)wlds;
        #pragma unroll
        for (int i = tid; i < (NE * DIM) / 4; i += BLOCK) {   // 4 iters each
            l4[i] = g4[i];
            l4[i + (NE * DIM) / 4] = n4[i];
        }
    }

    const int lane = tid & 63;
    const int wave = blockIdx.x * WAVES_PER_BLOCK + (tid >> 6);
    const int t0 = wave * TR;    // this wave's 4 tokens

    // early coalesced eps load: lane L<32 holds eps[t0*8 + L] (token t0+L/8, expert L%8)
    float my_eps = 0.f;
    if (lane < 32) my_eps = eps[t0 * NE + lane];

    __syncthreads();

    const float4* x4  = (const float4*)x;
    const float4* wl4 = (const float4*)wlds;

    // V[r*4+t] = partial dot of row r with token t0+t over this lane's D-slice
    float V[64];
    #pragma unroll
    for (int v = 0; v < 64; ++v) V[v] = 0.f;

    float4 xv[TR];
    #pragma unroll
    for (int t = 0; t < TR; ++t)
        xv[t] = x4[(t0 + t) * (DIM / 4) + lane];

    #pragma unroll
    for (int k = 0; k < DIM / 256; ++k) {
        float4 xn[TR];
        if (k < DIM / 256 - 1) {
            #pragma unroll
            for (int t = 0; t < TR; ++t)
                xn[t] = x4[(t0 + t) * (DIM / 4) + (k + 1) * 64 + lane];
        }
        #pragma unroll
        for (int r = 0; r < NROWS; ++r) {
            const float4 w = wl4[r * (DIM / 4) + k * 64 + lane];
            #pragma unroll
            for (int t = 0; t < TR; ++t) {
                float a = V[r * 4 + t];
                a = fmaf(xv[t].x, w.x, a);
                a = fmaf(xv[t].y, w.y, a);
                a = fmaf(xv[t].z, w.z, a);
                a = fmaf(xv[t].w, w.w, a);
                V[r * 4 + t] = a;
            }
        }
        if (k < DIM / 256 - 1) {
            #pragma unroll
            for (int t = 0; t < TR; ++t) xv[t] = xn[t];
        }
    }

    // ---- pack-halving reduction: 126 shuffles; lane L ends with value L summed ----
    #pragma unroll
    for (int s = 0; s < 6; ++s) {
        const int m = 1 << s;
        const int n = 64 >> s;
        #pragma unroll
        for (int j = 0; j < n / 2; ++j) {
            const float A = V[2 * j];
            const float B = V[2 * j + 1];
            const float As = __shfl_xor(A, m, 64);
            const float Bs = __shfl_xor(B, m, 64);
            V[j] = (lane & m) ? (B + Bs) : (A + As);
        }
    }
    const float mine = V[0];                 // lane L: value L = row (L>>2), token t0+(L&3)

    // lanes <32 hold gate sums (rows 0..7); partner lane+32 holds matching noise sum
    const float other = __shfl_xor(mine, 32, 64);

    if (lane < 32) {
        const int e = lane >> 2;
        const int t = lane & 3;
        const int tok = t0 + t;

        // redistribute eps: need eps[t*8+e], held by lane t*8+e
        const float ev = __shfl(my_eps, (t << 3) | e, 64);

        const float nv = other;
        const float sp = fmaxf(nv, 0.f) + log1pf(expf(-fabsf(nv)));  // stable softplus
        const float logit = fmaf(sp, ev, mine);

        // top-2 merge across the 8 lanes sharing token t (lanes differ in bits 2..4)
        float v1 = logit, v2 = -INFINITY;
        int   i1 = e,     i2 = 7;
        #pragma unroll
        for (int sm = 2; sm <= 4; ++sm) {
            const int m = 1 << sm;
            const float ov1 = __shfl_xor(v1, m, 64);
            const float ov2 = __shfl_xor(v2, m, 64);
            const int   oi1 = __shfl_xor(i1, m, 64);
            const int   oi2 = __shfl_xor(i2, m, 64);
            // merge two (desc-value, asc-index) sorted pairs
            const bool firstA = (v1 > ov1) || (v1 == ov1 && i1 < oi1);
            const float nv1 = firstA ? v1  : ov1;
            const int   ni1 = firstA ? i1  : oi1;
            const float ca  = firstA ? ov1 : v1;    // losing head
            const int   cia = firstA ? oi1 : i1;
            const float cb  = firstA ? v2  : ov2;   // winner's second
            const int   cib = firstA ? i2  : oi2;
            const bool secondA = (ca > cb) || (ca == cb && cia < cib);
            v1 = nv1; i1 = ni1;
            v2 = secondA ? ca : cb;
            i2 = secondA ? cia : cib;
        }

        if (e == 0) {
            out[2 * tok]     = v1;
            out[2 * tok + 1] = v2;
            out[2 * TOKENS + 2 * tok]     = (float)i1;
            out[2 * TOKENS + 2 * tok + 1] = (float)i2;
        }
    }
}

extern "C" void kernel_launch(void* const* d_in, const int* in_sizes, int n_in,
                              void* d_out, int out_size, void* d_ws, size_t ws_size,
                              hipStream_t stream) {
    const float* x       = (const float*)d_in[0];
    const float* w_g     = (const float*)d_in[1];
    const float* w_noise = (const float*)d_in[2];
    const float* eps     = (const float*)d_in[3];
    float* out = (float*)d_out;

    router_kernel<<<GRID, BLOCK, 0, stream>>>(x, w_g, w_noise, eps, out);
}